// Round 3
// baseline (417.411 us; speedup 1.0000x reference)
//
#include <hip/hip_runtime.h>
#include <math.h>

#define NQ 12
#define NSTATE 4096
#define NTHREADS 256
#define NL 3

typedef float v2f __attribute__((ext_vector_type(2)));
typedef float v4f __attribute__((ext_vector_type(4)));

// ---------------------------------------------------------------------------
// Setup kernel: build the 36 fused 1q gate matrices g = RY(p2)@RZ(p1)@RY(p0)
// into d_ws as 8 floats each: [g00r,g00i, g01r,g01i, g10r,g10i, g11r,g11i].
// ---------------------------------------------------------------------------
__global__ void make_gates(const float* __restrict__ params, float* __restrict__ gates) {
    int id = threadIdx.x;
    if (id >= NL * NQ) return;
    float p0 = params[id * 3 + 0];
    float p1 = params[id * 3 + 1];
    float p2 = params[id * 3 + 2];
    float c0 = cosf(0.5f * p0), s0 = sinf(0.5f * p0);
    float ch = cosf(0.5f * p1), sh = sinf(0.5f * p1);
    float c2 = cosf(0.5f * p2), s2 = sinf(0.5f * p2);
    float pr = ch, pi = -sh;   // p = exp(-i p1/2)
    float qr = ch, qi = sh;    // q = conj(p)
    float A = c2 * c0, Bc = s2 * s0, Cc = c2 * s0, D = s2 * c0;
    float* g = gates + id * 8;
    g[0] = A * pr - Bc * qr;  g[1] = A * pi - Bc * qi;
    g[2] = -Cc * pr - D * qr; g[3] = -Cc * pi - D * qi;
    g[4] = D * pr + Cc * qr;  g[5] = D * pi + Cc * qi;
    g[6] = -Bc * pr + A * qr; g[7] = -Bc * pi + A * qi;
}

__device__ __forceinline__ int sfx(int v) {  // suffix-xor = CNOT-chain permutation
    v ^= v >> 1; v ^= v >> 2; v ^= v >> 4; v ^= v >> 8;
    return v;
}

// ---- gate application on a register pair (A=|bit 0>, B=|bit 1>) ----------
// n0 = g00*A + g01*B ; n1 = g10*A + g11*B  (complex), expressed as packed
// float2 ops: cmplx_mul(g, a) = gr*a + gi*J(a), J(a) = (-a.y, a.x).
#define GP(A, B) do {                                                        \
    v2f ja_; ja_.x = -A.y; ja_.y = A.x;                                      \
    v2f jb_; jb_.x = -B.y; jb_.y = B.x;                                      \
    v2f n0_ = A * g00r + ja_ * g00i + B * g01r + jb_ * g01i;                 \
    v2f n1_ = A * g10r + ja_ * g10i + B * g11r + jb_ * g11i;                 \
    A = n0_; B = n1_;                                                        \
} while (0)

// Gate coefs from GLOBAL memory with wave-uniform address -> s_load -> SGPRs.
#define LOADG(gp)                                                            \
    const float g00r = (gp)[0], g00i = (gp)[1], g01r = (gp)[2],              \
                g01i = (gp)[3], g10r = (gp)[4], g10i = (gp)[5],              \
                g11r = (gp)[6], g11i = (gp)[7];

#define GATE0(gp) do { LOADG(gp) GP(s0,s1); GP(s2,s3); GP(s4,s5); GP(s6,s7); \
                       GP(s8,s9); GP(s10,s11); GP(s12,s13); GP(s14,s15); } while (0)
#define GATE1(gp) do { LOADG(gp) GP(s0,s2); GP(s1,s3); GP(s4,s6); GP(s5,s7); \
                       GP(s8,s10); GP(s9,s11); GP(s12,s14); GP(s13,s15); } while (0)
#define GATE2(gp) do { LOADG(gp) GP(s0,s4); GP(s1,s5); GP(s2,s6); GP(s3,s7); \
                       GP(s8,s12); GP(s9,s13); GP(s10,s14); GP(s11,s15); } while (0)
#define GATE3(gp) do { LOADG(gp) GP(s0,s8); GP(s1,s9); GP(s2,s10); GP(s3,s11); \
                       GP(s4,s12); GP(s5,s13); GP(s6,s14); GP(s7,s15); } while (0)

#define FOR16(M) M(0,s0) M(1,s1) M(2,s2) M(3,s3) M(4,s4) M(5,s5) M(6,s6) M(7,s7) \
                 M(8,s8) M(9,s9) M(10,s10) M(11,s11) M(12,s12) M(13,s13) M(14,s14) M(15,s15)
#define FOR8(M) M(0,s0,s1) M(1,s2,s3) M(2,s4,s5) M(3,s6,s7) \
                M(4,s8,s9) M(5,s10,s11) M(6,s12,s13) M(7,s14,s15)

// Physical LDS mapping: P(idx) = idx ^ (((idx>>4)&7) << 1)  (proven in R1/R2:
// SQ_LDS_BANK_CONFLICT ~256 cyc/block = negligible).
#define STORE_L0(k, A, B) { v4f v_; v_.x = A.x; v_.y = A.y; v_.z = B.x; v_.w = B.y; \
                            sbufq[(t << 3) | ((k) ^ tw)] = v_; }
#define LOAD_L0(k, A, B)  { v4f v_ = sbufq[(t << 3) | ((k) ^ tw)]; \
                            A.x = v_.x; A.y = v_.y; B.x = v_.z; B.y = v_.w; }
#define LOAD_L1(r, SV)  SV = sbuf[(base1 | ((r) << 4)) ^ (((r) & 7) << 1)];
#define STORE_L1(r, SV) sbuf[(base1 | ((r) << 4)) ^ (((r) & 7) << 1)] = SV;
#define LOAD_L2(r, SV)  SV = sbuf[(((r) << 8) | t) ^ s2sw];
#define STORE_PERM(r, SV) { int m_ = sfx(((r) << 8) | t); \
                            sbuf[m_ ^ (((m_ >> 4) & 7) << 1)] = SV; }

#define SELW(m, bit, w) ((((m) >> (bit)) & 1) ? -(w) : (w))
#define MEAS(r, SV) { int m_ = sfx(((r) << 8) | t); \
    float p2_ = fmaf(SV.x, SV.x, SV.y * SV.y); \
    float ws_ = SELW(m_,11,w0) + SELW(m_,10,w1) + SELW(m_,9,w2) + SELW(m_,8,w3) \
              + SELW(m_,7,w4) + SELW(m_,6,w5) + SELW(m_,5,w6) + SELW(m_,4,w7) \
              + SELW(m_,3,w8) + SELW(m_,2,w9) + SELW(m_,1,w10) + SELW(m_,0,w11); \
    acc = fmaf(p2_, ws_, acc); }

// Init helpers (r is a literal -> everything folds)
#define PC4(r) ((((r)) & 1) + (((r) >> 1) & 1) + (((r) >> 2) & 1) + (((r) >> 3) & 1))
#define QHI(r) ((((r) >> 2) & 3) == 0 ? hi0 : (((r) >> 2) & 3) == 1 ? hi1 : \
                (((r) >> 2) & 3) == 2 ? hi2 : hi3)
#define QLO(r) (((r) & 3) == 0 ? lo0 : ((r) & 3) == 1 ? lo1 : \
                ((r) & 3) == 2 ? lo2 : lo3)
#define INIT(r, SV) { \
    float mag_ = common * (QHI(r) * QLO(r)); \
    int k_ = (pct + PC4(r)) & 3; \
    SV.x = (k_ & 1) ? 0.f : ((k_ & 2) ? -mag_ : mag_); \
    SV.y = (k_ & 1) ? ((k_ & 2) ? mag_ : -mag_) : 0.f; }

__attribute__((amdgpu_waves_per_eu(4, 4)))
__global__ void __launch_bounds__(NTHREADS)
qsim_kernel(const float* __restrict__ x,
            const float* __restrict__ gates,
            const float* __restrict__ head_w,
            const float* __restrict__ head_b,
            float* __restrict__ out) {
    __shared__ __align__(16) v2f sbuf[NSTATE];   // 32 KB transpose buffer
    __shared__ float csx[NQ], snx[NQ];
    __shared__ float wred[NTHREADS / 64];
    v4f* sbufq = (v4f*)sbuf;

    const int t = threadIdx.x;
    const int b = blockIdx.x;

    if (t < NQ) {
        float xv = 0.5f * x[b * NQ + t];
        csx[t] = cosf(xv);
        snx[t] = sinf(xv);
    }
    __syncthreads();

    // ---- Init: product state from RX encoding, layout L0: idx = t*16 + r ----
    // wire i <-> state bit (11-i); amp = prod(c/s) * (-i)^popcount(idx).
    v2f s0, s1, s2, s3, s4, s5, s6, s7, s8, s9, s10, s11, s12, s13, s14, s15;
    {
        float common = 1.f;
#pragma unroll
        for (int i = 0; i < 8; ++i)
            common *= ((t >> (7 - i)) & 1) ? snx[i] : csx[i];
        const int pct = __popc(t);
        const float hi0 = csx[8] * csx[9], hi1 = csx[8] * snx[9],
                    hi2 = snx[8] * csx[9], hi3 = snx[8] * snx[9];
        const float lo0 = csx[10] * csx[11], lo1 = csx[10] * snx[11],
                    lo2 = snx[10] * csx[11], lo3 = snx[10] * snx[11];
        FOR16(INIT)
    }

    const int tw = t & 7;
    const int base1 = ((t >> 4) << 8) | (t & 15);
    const int s2sw = ((t >> 4) & 7) << 1;

#pragma unroll
    for (int l = 0; l < NL; ++l) {
        const float* gl = gates + l * (NQ * 8);

        // ---- L0: reg bit bb = state bit bb = wire 11-bb ----
        GATE0(gl + 11 * 8); GATE1(gl + 10 * 8); GATE2(gl + 9 * 8); GATE3(gl + 8 * 8);

        __syncthreads();
        FOR8(STORE_L0)
        __syncthreads();
        FOR16(LOAD_L1)

        // ---- L1: reg bit bb = state bit 4+bb = wire 7-bb ----
        GATE0(gl + 7 * 8); GATE1(gl + 6 * 8); GATE2(gl + 5 * 8); GATE3(gl + 4 * 8);

        __syncthreads();
        FOR16(STORE_L1)
        __syncthreads();
        FOR16(LOAD_L2)

        // ---- L2: reg bit bb = state bit 8+bb = wire 3-bb ----
        GATE0(gl + 3 * 8); GATE1(gl + 2 * 8); GATE2(gl + 1 * 8); GATE3(gl + 0 * 8);

        if (l < NL - 1) {
            // Layer-end transpose back to L0, folding the CNOT-chain
            // permutation (suffix-xor) into the store addresses.
            __syncthreads();
            FOR16(STORE_PERM)
            __syncthreads();
            FOR8(LOAD_L0)
        }
    }

    // ---- Measurement: last CNOT permutation folded in analytically.
    // out[b] = sum_idx |amp|^2 * wsum(perm(idx)) + bias
    const float w0 = head_w[0], w1 = head_w[1], w2 = head_w[2], w3 = head_w[3],
                w4 = head_w[4], w5 = head_w[5], w6 = head_w[6], w7 = head_w[7],
                w8 = head_w[8], w9 = head_w[9], w10 = head_w[10], w11 = head_w[11];
    float acc = 0.f;
    FOR16(MEAS)

#pragma unroll
    for (int off = 32; off >= 1; off >>= 1) acc += __shfl_xor(acc, off, 64);
    if ((t & 63) == 0) wred[t >> 6] = acc;
    __syncthreads();
    if (t == 0) out[b] = wred[0] + wred[1] + wred[2] + wred[3] + head_b[0];
}

extern "C" void kernel_launch(void* const* d_in, const int* in_sizes, int n_in,
                              void* d_out, int out_size, void* d_ws, size_t ws_size,
                              hipStream_t stream) {
    const float* x = (const float*)d_in[0];
    const float* params = (const float*)d_in[1];
    const float* head_w = (const float*)d_in[2];
    const float* head_b = (const float*)d_in[3];
    float* out = (float*)d_out;
    float* gates = (float*)d_ws;  // 288 floats
    int B = in_sizes[0] / NQ;

    hipLaunchKernelGGL(make_gates, dim3(1), dim3(64), 0, stream, params, gates);
    hipLaunchKernelGGL(qsim_kernel, dim3(B), dim3(NTHREADS), 0, stream,
                       x, gates, head_w, head_b, out);
}

// Round 4
// 305.489 us; speedup vs baseline: 1.3664x; 1.3664x over previous
//
#include <hip/hip_runtime.h>
#include <math.h>

#define NQ 12
#define NSTATE 4096
#define NTHREADS 512
#define NL 3

typedef float v2f __attribute__((ext_vector_type(2)));
typedef float v4f __attribute__((ext_vector_type(4)));

// ---------------------------------------------------------------------------
// Setup kernel: build the 36 fused 1q gate matrices g = RY(p2)@RZ(p1)@RY(p0)
// into d_ws as 8 floats each: [g00r,g00i, g01r,g01i, g10r,g10i, g11r,g11i].
// ---------------------------------------------------------------------------
__global__ void make_gates(const float* __restrict__ params, float* __restrict__ gates) {
    int id = threadIdx.x;
    if (id >= NL * NQ) return;
    float p0 = params[id * 3 + 0];
    float p1 = params[id * 3 + 1];
    float p2 = params[id * 3 + 2];
    float c0 = cosf(0.5f * p0), s0 = sinf(0.5f * p0);
    float ch = cosf(0.5f * p1), sh = sinf(0.5f * p1);
    float c2 = cosf(0.5f * p2), s2 = sinf(0.5f * p2);
    float pr = ch, pi = -sh;   // p = exp(-i p1/2)
    float qr = ch, qi = sh;    // q = conj(p)
    float A = c2 * c0, Bc = s2 * s0, Cc = c2 * s0, D = s2 * c0;
    float* g = gates + id * 8;
    g[0] = A * pr - Bc * qr;  g[1] = A * pi - Bc * qi;
    g[2] = -Cc * pr - D * qr; g[3] = -Cc * pi - D * qi;
    g[4] = D * pr + Cc * qr;  g[5] = D * pi + Cc * qi;
    g[6] = -Bc * pr + A * qr; g[7] = -Bc * pi + A * qi;
}

__device__ __forceinline__ int sfx(int v) {  // suffix-xor = CNOT-chain permutation
    v ^= v >> 1; v ^= v >> 2; v ^= v >> 4; v ^= v >> 8;
    return v;
}

// LDS swizzle: phys = idx ^ ((idx>>3)&3)<<1 ^ ((idx>>6)&1)<<3.
// Paper-verified conflict-free (each bank-pair hit exactly 4x per wave64
// float2 access) for all four layouts below AND the sfx-permuted store;
// bit 0 untouched so L0's (even,odd) pairs stay float4-contiguous.
__device__ __forceinline__ int swz(int idx) {
    return idx ^ ((((idx >> 3) & 3) << 1) | (((idx >> 6) & 1) << 3));
}

// ---- complex 2x2 gate on a register pair ---------------------------------
// n0 = g00*A + g01*B ; n1 = g10*A + g11*B ; cmul(g,a) = gr*a + gi*J(a),
// J(a) = (-a.y, a.x).
#define GP(A, B) do {                                                        \
    v2f ja_; ja_.x = -A.y; ja_.y = A.x;                                      \
    v2f jb_; jb_.x = -B.y; jb_.y = B.x;                                      \
    v2f n0_ = A * g00r + ja_ * g00i + B * g01r + jb_ * g01i;                 \
    v2f n1_ = A * g10r + ja_ * g10i + B * g11r + jb_ * g11i;                 \
    A = n0_; B = n1_;                                                        \
} while (0)

// Wave-uniform global reads -> s_load -> SGPR coefficients (0 VGPR cost).
#define LOADG(gp)                                                            \
    const float g00r = (gp)[0], g00i = (gp)[1], g01r = (gp)[2],              \
                g01i = (gp)[3], g10r = (gp)[4], g10i = (gp)[5],              \
                g11r = (gp)[6], g11i = (gp)[7];

// Gate on register bit 0/1/2 of the 8-amp register file.
#define GATEB0(gp) do { LOADG(gp) GP(s0,s1); GP(s2,s3); GP(s4,s5); GP(s6,s7); } while (0)
#define GATEB1(gp) do { LOADG(gp) GP(s0,s2); GP(s1,s3); GP(s4,s6); GP(s5,s7); } while (0)
#define GATEB2(gp) do { LOADG(gp) GP(s0,s4); GP(s1,s5); GP(s2,s6); GP(s3,s7); } while (0)

#define FOR8(M) M(0,s0) M(1,s1) M(2,s2) M(3,s3) M(4,s4) M(5,s5) M(6,s6) M(7,s7)
#define FOR4Q(M) M(0,s0,s1) M(1,s2,s3) M(2,s4,s5) M(3,s6,s7)

// Layouts (idx = 12-bit state index, t = thread 0..511, r = reg 0..7):
//   L0: idx = (t<<3) | r            (reg bits = state bits 2..0)
//   L1: idx = ((t>>3)<<6)|(r<<3)|(t&7)     (reg bits = state bits 5..3)
//   L2: idx = ((t>>6)<<9)|(r<<6)|(t&63)    (reg bits = state bits 8..6)
//   L3: idx = (r<<9) | t            (reg bits = state bits 11..9)
#define STORE_L0(k, A, B) { v4f v_; v_.x = A.x; v_.y = A.y; v_.z = B.x; v_.w = B.y; \
                            sbufq[swz((t << 3) | ((k) << 1)) >> 1] = v_; }
#define LOAD_L0(k, A, B)  { v4f v_ = sbufq[swz((t << 3) | ((k) << 1)) >> 1]; \
                            A.x = v_.x; A.y = v_.y; B.x = v_.z; B.y = v_.w; }
#define LOAD_L1(r, SV)  SV = sbuf[swz(b1 | ((r) << 3))];
#define STORE_L1(r, SV) sbuf[swz(b1 | ((r) << 3))] = SV;
#define LOAD_L2(r, SV)  SV = sbuf[swz(b2 | ((r) << 6))];
#define STORE_L2(r, SV) sbuf[swz(b2 | ((r) << 6))] = SV;
#define LOAD_L3(r, SV)  SV = sbuf[swz(((r) << 9) | t)];
#define STORE_PERM(r, SV) { int m_ = sfx(((r) << 9) | t); sbuf[swz(m_)] = SV; }

#define SELW(m, bit, w) ((((m) >> (bit)) & 1) ? -(w) : (w))
#define MEAS(r, SV) { int m_ = sfx(((r) << 9) | t); \
    float p2_ = fmaf(SV.x, SV.x, SV.y * SV.y); \
    float ws_ = SELW(m_,11,w0) + SELW(m_,10,w1) + SELW(m_,9,w2) + SELW(m_,8,w3) \
              + SELW(m_,7,w4) + SELW(m_,6,w5) + SELW(m_,5,w6) + SELW(m_,4,w7) \
              + SELW(m_,3,w8) + SELW(m_,2,w9) + SELW(m_,1,w10) + SELW(m_,0,w11); \
    acc = fmaf(p2_, ws_, acc); }

// Init helpers: r is a literal, everything folds.
#define PC3(r) (((r) & 1) + (((r) >> 1) & 1) + (((r) >> 2) & 1))
#define LO(r) ((r) == 0 ? lo0 : (r) == 1 ? lo1 : (r) == 2 ? lo2 : (r) == 3 ? lo3 : \
               (r) == 4 ? lo4 : (r) == 5 ? lo5 : (r) == 6 ? lo6 : lo7)
#define INIT(r, SV) { \
    float mag_ = common * LO(r); \
    int k_ = (pct + PC3(r)) & 3; \
    SV.x = (k_ & 1) ? 0.f : ((k_ & 2) ? -mag_ : mag_); \
    SV.y = (k_ & 1) ? ((k_ & 2) ? mag_ : -mag_) : 0.f; }

__global__ void __launch_bounds__(NTHREADS)
qsim_kernel(const float* __restrict__ x,
            const float* __restrict__ gates,
            const float* __restrict__ head_w,
            const float* __restrict__ head_b,
            float* __restrict__ out) {
    __shared__ __align__(16) v2f sbuf[NSTATE];   // 32 KB transpose buffer
    __shared__ float csx[NQ], snx[NQ];
    __shared__ float wred[NTHREADS / 64];
    v4f* sbufq = (v4f*)sbuf;

    const int t = threadIdx.x;
    const int b = blockIdx.x;

    if (t < NQ) {
        float xv = 0.5f * x[b * NQ + t];
        csx[t] = cosf(xv);
        snx[t] = sinf(xv);
    }
    __syncthreads();

    // ---- Init: product state from RX encoding, layout L0 ----
    // wire i <-> state bit (11-i); amp = prod(c/s) * (-i)^popcount(idx).
    // State bits 11..3 = t bits 8..0 (wires 0..8); bits 2..0 = r (wires 9..11).
    v2f s0, s1, s2, s3, s4, s5, s6, s7;
    {
        float common = 1.f;
#pragma unroll
        for (int i = 0; i < 9; ++i)
            common *= ((t >> (8 - i)) & 1) ? snx[i] : csx[i];
        const int pct = __popc(t);
        const float c9 = csx[9], s9v = snx[9], c10 = csx[10], s10v = snx[10],
                    c11 = csx[11], s11v = snx[11];
        const float lo0 = c9 * c10 * c11,  lo1 = c9 * c10 * s11v,
                    lo2 = c9 * s10v * c11, lo3 = c9 * s10v * s11v,
                    lo4 = s9v * c10 * c11, lo5 = s9v * c10 * s11v,
                    lo6 = s9v * s10v * c11, lo7 = s9v * s10v * s11v;
        FOR8(INIT)
    }

    const int b1 = ((t >> 3) << 6) | (t & 7);
    const int b2 = ((t >> 6) << 9) | (t & 63);

#pragma unroll 1
    for (int l = 0; l < NL; ++l) {
        const float* gl = gates + l * (NQ * 8);

        // ---- L0: reg bit j = state bit j = wire 11-j -> wires 9,10,11 ----
        GATEB2(gl + 9 * 8); GATEB1(gl + 10 * 8); GATEB0(gl + 11 * 8);

        __syncthreads();
        FOR4Q(STORE_L0)
        __syncthreads();
        FOR8(LOAD_L1)

        // ---- L1: reg bit j = state bit 3+j = wire 8-j -> wires 6,7,8 ----
        GATEB2(gl + 6 * 8); GATEB1(gl + 7 * 8); GATEB0(gl + 8 * 8);

        __syncthreads();
        FOR8(STORE_L1)
        __syncthreads();
        FOR8(LOAD_L2)

        // ---- L2: reg bit j = state bit 6+j = wire 5-j -> wires 3,4,5 ----
        GATEB2(gl + 3 * 8); GATEB1(gl + 4 * 8); GATEB0(gl + 5 * 8);

        __syncthreads();
        FOR8(STORE_L2)
        __syncthreads();
        FOR8(LOAD_L3)

        // ---- L3: reg bit j = state bit 9+j = wire 2-j -> wires 0,1,2 ----
        GATEB2(gl + 0 * 8); GATEB1(gl + 1 * 8); GATEB0(gl + 2 * 8);

        if (l < NL - 1) {
            // Transpose back to L0 with the CNOT-chain permutation
            // (suffix-xor) folded into the store addresses.
            __syncthreads();
            FOR8(STORE_PERM)
            __syncthreads();
            FOR4Q(LOAD_L0)
        }
    }

    // ---- Measurement: last CNOT permutation folded in analytically.
    // out[b] = sum_idx |amp|^2 * wsum(perm(idx)) + bias
    const float w0 = head_w[0], w1 = head_w[1], w2 = head_w[2], w3 = head_w[3],
                w4 = head_w[4], w5 = head_w[5], w6 = head_w[6], w7 = head_w[7],
                w8 = head_w[8], w9 = head_w[9], w10 = head_w[10], w11 = head_w[11];
    float acc = 0.f;
    FOR8(MEAS)

#pragma unroll
    for (int off = 32; off >= 1; off >>= 1) acc += __shfl_xor(acc, off, 64);
    if ((t & 63) == 0) wred[t >> 6] = acc;
    __syncthreads();
    if (t == 0) {
        float r_ = head_b[0];
#pragma unroll
        for (int i = 0; i < NTHREADS / 64; ++i) r_ += wred[i];
        out[b] = r_;
    }
}

extern "C" void kernel_launch(void* const* d_in, const int* in_sizes, int n_in,
                              void* d_out, int out_size, void* d_ws, size_t ws_size,
                              hipStream_t stream) {
    const float* x = (const float*)d_in[0];
    const float* params = (const float*)d_in[1];
    const float* head_w = (const float*)d_in[2];
    const float* head_b = (const float*)d_in[3];
    float* out = (float*)d_out;
    float* gates = (float*)d_ws;  // 288 floats
    int B = in_sizes[0] / NQ;

    hipLaunchKernelGGL(make_gates, dim3(1), dim3(64), 0, stream, params, gates);
    hipLaunchKernelGGL(qsim_kernel, dim3(B), dim3(NTHREADS), 0, stream,
                       x, gates, head_w, head_b, out);
}

// Round 5
// 176.000 us; speedup vs baseline: 2.3717x; 1.7357x over previous
//
#include <hip/hip_runtime.h>
#include <math.h>

#define NQ 12
#define NTHREADS 512
#define NL 3

typedef _Float16 h8 __attribute__((ext_vector_type(8)));
typedef _Float16 h4 __attribute__((ext_vector_type(4)));
typedef float f4 __attribute__((ext_vector_type(4)));

// ---------------------------------------------------------------------------
// make_gates: build 36 fused 2x2 gates G = RY(p2)@RZ(p1)@RY(p0) (R4-verified),
// then 9 group matrices (layer l, group g of 4 wires) as real 32x32 f16:
//   W[s][n][k], s = l*3+g, n = reim'*16+t', k = reim*16+t,
//   U[t'][t] = prod_j G_{l, wire=11-(4g+j)}[t'_j][t_j]  (complex 16x16)
//   W blocks: [[Ur, -Ui],[Ui, Ur]]  (row n, col k)
// Stored exactly as the MFMA B-operand wants: B[k][n] = W[n][k], k-contiguous.
// ---------------------------------------------------------------------------
__global__ void make_gates(const float* __restrict__ params, _Float16* __restrict__ Wout) {
    __shared__ float Gs[36 * 8];
    const int tid = threadIdx.x;
    if (tid < 36) {
        float p0 = params[tid * 3 + 0];
        float p1 = params[tid * 3 + 1];
        float p2 = params[tid * 3 + 2];
        float c0 = cosf(0.5f * p0), s0 = sinf(0.5f * p0);
        float ch = cosf(0.5f * p1), sh = sinf(0.5f * p1);
        float c2 = cosf(0.5f * p2), s2 = sinf(0.5f * p2);
        float pr = ch, pi = -sh;   // p = exp(-i p1/2)
        float qr = ch, qi = sh;    // q = conj(p)
        float A = c2 * c0, Bc = s2 * s0, Cc = c2 * s0, D = s2 * c0;
        float* g = &Gs[tid * 8];
        g[0] = A * pr - Bc * qr;  g[1] = A * pi - Bc * qi;   // g00
        g[2] = -Cc * pr - D * qr; g[3] = -Cc * pi - D * qi;  // g01
        g[4] = D * pr + Cc * qr;  g[5] = D * pi + Cc * qi;   // g10
        g[6] = -Bc * pr + A * qr; g[7] = -Bc * pi + A * qi;  // g11
    }
    __syncthreads();
    for (int e = tid; e < 9 * 1024; e += 256) {
        int s = e >> 10, idx = e & 1023;
        int n = idx >> 5, k = idx & 31;
        int rp = n >> 4, tp = n & 15, rr = k >> 4, tt = k & 15;
        int l = s / 3, g = s - 3 * l;
        float ur = 1.f, ui = 0.f;
#pragma unroll
        for (int jj = 0; jj < 4; ++jj) {
            int wire = 11 - (4 * g + jj);           // bit jj of t <-> wire 11-(4g+jj)
            const float* gp = &Gs[(l * 12 + wire) * 8];
            int rb = (tp >> jj) & 1, cb = (tt >> jj) & 1;
            float gr = gp[(rb * 2 + cb) * 2], gi = gp[(rb * 2 + cb) * 2 + 1];
            float nr = ur * gr - ui * gi;
            float ni = ur * gi + ui * gr;
            ur = nr; ui = ni;
        }
        float val = (rp == 0) ? ((rr == 0) ? ur : -ui)
                              : ((rr == 0) ? ui : ur);
        Wout[e] = (_Float16)val;
    }
}

// suffix-xor = CNOT-chain permutation (R4-verified convention)
__device__ __forceinline__ int sfx(int v) {
    v ^= v >> 1; v ^= v >> 2; v ^= v >> 4; v ^= v >> 8;
    return v;
}

// LDS swizzle on the state buffer (f16 element offsets): flips 8-f16-chunk
// bits 3,4 by XOR of higher offset bits; keeps 4-f16 runs (bits 0..1) and
// 8-f16 runs (bits 0..2) contiguous -> b64/b128-safe. Spreads banks to
// <=2-way on the A-read pattern (2-way is free, m136).
__device__ __forceinline__ int swzf(int off) {
    return off ^ (((((off >> 5) ^ (off >> 7) ^ (off >> 9)) & 3)) << 3);
}

// Layouts (step g, state index i, 8-bit row m, 4-bit t = target bits, reim):
//   off_g = m*32 + reim*16 + t
//   g=0: t = i[3:0]  (wires 8..11),  m = i>>4           (i = m<<4 | t)
//   g=1: t = i[7:4]  (wires 4..7),   m = i[9:8] | i[3:0]<<2 | i[11:10]<<6
//   g=2: t = i[11:8] (wires 0..3),   m = i[7:0]
// Row-orderings chosen so a lane's 4 D-rows (consecutive m) land at
// consecutive offsets in the NEXT layout -> b64 stores.

__global__ void __launch_bounds__(NTHREADS)
qsim_kernel(const float* __restrict__ x,
            const _Float16* __restrict__ Wg,
            const float* __restrict__ head_w,
            const float* __restrict__ head_b,
            float* __restrict__ out) {
    __shared__ __align__(16) _Float16 Sst[8192];   // 16 KB state (256 x 32 f16)
    __shared__ __align__(16) _Float16 Wl[9216];    // 18 KB group matrices
    __shared__ float wlo[64], whi[64];
    __shared__ float csx[NQ], snx[NQ];
    __shared__ float wred[NTHREADS / 64];

    const int t = threadIdx.x, b = blockIdx.x;

    for (int i = t; i < 9216 / 2; i += NTHREADS)
        ((uint32_t*)Wl)[i] = ((const uint32_t*)Wg)[i];
    if (t < NQ) {
        float xv = 0.5f * x[b * NQ + t];
        csx[t] = cosf(xv);
        snx[t] = sinf(xv);
    }
    if (t >= 64 && t < 128) {        // wsum low LUT: bits 0..5 <-> wires 11..6
        int v = t - 64; float s = 0.f;
#pragma unroll
        for (int be = 0; be < 6; ++be)
            s += ((v >> be) & 1) ? -head_w[11 - be] : head_w[11 - be];
        wlo[v] = s;
    }
    if (t >= 128 && t < 192) {       // wsum high LUT: bits 6..11 <-> wires 5..0
        int v = t - 128; float s = 0.f;
#pragma unroll
        for (int be = 0; be < 6; ++be)
            s += ((v >> be) & 1) ? -head_w[5 - be] : head_w[5 - be];
        whi[v] = s;
    }
    __syncthreads();

    // ---- Init: product state (RX encoding), L_0 layout ----
    // amp(i) = (-i)^popc(i) * prod_w (bit_{11-w}(i) ? sin : cos)(x_w/2)
    {
        int m = t & 255, reim = t >> 8;
        float magm = 1.f;
#pragma unroll
        for (int j = 0; j < 8; ++j)       // m bit j = state bit 4+j = wire 7-j
            magm *= ((m >> j) & 1) ? snx[7 - j] : csx[7 - j];
        float A2[4], B2[4];
#pragma unroll
        for (int v = 0; v < 4; ++v) {     // t bits 0,1 = wires 11,10; bits 2,3 = wires 9,8
            A2[v] = ((v & 1) ? snx[11] : csx[11]) * ((v & 2) ? snx[10] : csx[10]);
            B2[v] = ((v & 1) ? snx[9] : csx[9]) * ((v & 2) ? snx[8] : csx[8]);
        }
        int pm = __popc(m);
        h8 w0, w1;
#pragma unroll
        for (int tau = 0; tau < 16; ++tau) {
            float mag = magm * A2[tau & 3] * B2[tau >> 2];
            int p = (pm + __popc(tau)) & 3;
            bool nz = ((p & 1) == reim);
            bool neg = ((((p >> 1) & 1) ^ reim) != 0);
            float v = nz ? (neg ? -mag : mag) : 0.f;
            if (tau < 8) w0[tau] = (_Float16)v; else w1[tau - 8] = (_Float16)v;
        }
        int off = m * 32 + reim * 16;
        *(h8*)&Sst[swzf(off)] = w0;
        *(h8*)&Sst[swzf(off + 8)] = w1;
    }
    __syncthreads();

    const int u = t & 15;          // MFMA row/col lane id
    const int q = (t >> 4) & 3;    // MFMA quad
    const int wv = t >> 6;         // wave id (0..7); tiles wv and wv+8
    const int abase0 = swzf((wv * 16 + u) * 32 + q * 8);
    const int abase1 = swzf(((wv + 8) * 16 + u) * 32 + q * 8);
    const int wb = u * 32 + q * 8;
    const f4 Z = {0.f, 0.f, 0.f, 0.f};
    float racc = 0.f;

#define ST4F(off_, v0_, v1_, v2_, v3_) {                                     \
    h4 w_; w_.x = (_Float16)(v0_); w_.y = (_Float16)(v1_);                   \
    w_.z = (_Float16)(v2_); w_.w = (_Float16)(v3_);                          \
    *(h4*)&Sst[swzf(off_)] = w_; }

#define ST4(off_, c_) ST4F(off_, (c_).x, (c_).y, (c_).z, (c_).w)

#define MM(sW_)                                                              \
    {                                                                        \
        h8 bf0 = *(const h8*)&Wl[(sW_) + wb];                                \
        h8 bf1 = *(const h8*)&Wl[(sW_) + 512 + wb];                          \
        h8 a0 = *(const h8*)&Sst[abase0];                                    \
        h8 a1 = *(const h8*)&Sst[abase1];                                    \
        c00 = __builtin_amdgcn_mfma_f32_16x16x32_f16(a0, bf0, Z, 0, 0, 0);   \
        c01 = __builtin_amdgcn_mfma_f32_16x16x32_f16(a0, bf1, Z, 0, 0, 0);   \
        c10 = __builtin_amdgcn_mfma_f32_16x16x32_f16(a1, bf0, Z, 0, 0, 0);   \
        c11 = __builtin_amdgcn_mfma_f32_16x16x32_f16(a1, bf1, Z, 0, 0, 0);   \
        __syncthreads();                                                     \
    }

// layer-end store: CNOT suffix-xor folded in; 4 slots stay an aligned group,
// values XOR-permuted by e = s2(j0&3), s2(x) = x ^ (x>>1)
#define PST1(off_, e_, v_) {                                                 \
    bool e1_ = ((e_) & 1), e2_ = (((e_) & 2) != 0);                          \
    float b0_ = e1_ ? (v_).y : (v_).x, b1_ = e1_ ? (v_).x : (v_).y;          \
    float b2_ = e1_ ? (v_).w : (v_).z, b3_ = e1_ ? (v_).z : (v_).w;          \
    ST4F(off_, e2_ ? b2_ : b0_, e2_ ? b3_ : b1_,                             \
               e2_ ? b1_ : b3_, e2_ ? b0_ : b2_); }

#define PERMST(tau_, vh0_, vh1_) {                                           \
    int i0_ = u * 256 + (tau_) * 16 + q * 4;                                 \
    int j0_ = sfx(i0_);                                                      \
    int cc_ = j0_ & 3, e_ = cc_ ^ (cc_ >> 1);                                \
    int jb_ = j0_ ^ cc_;                                                     \
    int ob_ = ((jb_ >> 4) << 5) | (jb_ & 12);                                \
    PST1(ob_, e_, vh0_); PST1(ob_ + 16, e_, vh1_); }

#define MEAS(tau_, vh0_, vh1_) {                                             \
    int i0_ = u * 256 + (tau_) * 16 + q * 4;                                 \
    int j0_ = sfx(i0_);                                                      \
    int jl_ = j0_ & 63;                                                      \
    float wh_ = whi[j0_ >> 6];                                               \
    float W0_ = wlo[jl_] + wh_, W1_ = wlo[jl_ ^ 1] + wh_;                    \
    float W2_ = wlo[jl_ ^ 3] + wh_, W3_ = wlo[jl_ ^ 2] + wh_;                \
    racc = fmaf((vh0_).x * (vh0_).x + (vh1_).x * (vh1_).x, W0_, racc);       \
    racc = fmaf((vh0_).y * (vh0_).y + (vh1_).y * (vh1_).y, W1_, racc);       \
    racc = fmaf((vh0_).z * (vh0_).z + (vh1_).z * (vh1_).z, W2_, racc);       \
    racc = fmaf((vh0_).w * (vh0_).w + (vh1_).w * (vh1_).w, W3_, racc); }

#pragma unroll
    for (int l = 0; l < NL; ++l) {
        f4 c00, c01, c10, c11;
        // ---- g=0: wires 8..11 ----
        MM((l * 3 + 0) * 1024)
        {   // D rows (bits 4,5 of i) -> L_1 t-low bits
            int wv3 = wv & 3, wvh = wv >> 2;
            int mf0 = (wv3 | (u << 2) | (wvh << 6)) * 32;
            int mf1 = (wv3 | (u << 2) | ((wvh + 2) << 6)) * 32;
            ST4(mf0 + q * 4, c00); ST4(mf0 + 16 + q * 4, c01);
            ST4(mf1 + q * 4, c10); ST4(mf1 + 16 + q * 4, c11);
            __syncthreads();
        }
        // ---- g=1: wires 4..7 ----
        MM((l * 3 + 1) * 1024)
        {   // D rows (bits 8,9 of i) -> L_2 t-low bits
            int p4 = (wv * 4 + q) & 15;
            int bm = (p4 | (u << 4)) * 32 + (wv >> 2) * 4;
            ST4(bm, c00); ST4(bm + 16, c01);
            ST4(bm + 8, c10); ST4(bm + 24, c11);
            __syncthreads();
        }
        // ---- g=2: wires 0..3 ----
        MM((l * 3 + 2) * 1024)
        if (l < NL - 1) {
            PERMST(wv, c00, c01)
            PERMST(wv + 8, c10, c11)
            __syncthreads();
        } else {
            // measurement: |amp|^2 * wsum(sfx(i)), halves = re/im parts
            MEAS(wv, c00, c01)
            MEAS(wv + 8, c10, c11)
        }
    }

#pragma unroll
    for (int o = 32; o >= 1; o >>= 1) racc += __shfl_xor(racc, o, 64);
    if ((t & 63) == 0) wred[wv] = racc;
    __syncthreads();
    if (t == 0) {
        float r = head_b[0];
#pragma unroll
        for (int i = 0; i < NTHREADS / 64; ++i) r += wred[i];
        out[b] = r;
    }
}

extern "C" void kernel_launch(void* const* d_in, const int* in_sizes, int n_in,
                              void* d_out, int out_size, void* d_ws, size_t ws_size,
                              hipStream_t stream) {
    const float* x = (const float*)d_in[0];
    const float* params = (const float*)d_in[1];
    const float* head_w = (const float*)d_in[2];
    const float* head_b = (const float*)d_in[3];
    float* out = (float*)d_out;
    _Float16* gates = (_Float16*)d_ws;   // 9216 f16 = 18 KB
    int B = in_sizes[0] / NQ;

    hipLaunchKernelGGL(make_gates, dim3(1), dim3(256), 0, stream, params, gates);
    hipLaunchKernelGGL(qsim_kernel, dim3(B), dim3(NTHREADS), 0, stream,
                       x, gates, head_w, head_b, out);
}

// Round 6
// 142.803 us; speedup vs baseline: 2.9230x; 1.2325x over previous
//
#include <hip/hip_runtime.h>
#include <math.h>

#define NQ 12
#define NTHREADS 512
#define NL 3

typedef _Float16 h8 __attribute__((ext_vector_type(8)));
typedef _Float16 h4 __attribute__((ext_vector_type(4)));
typedef float f4 __attribute__((ext_vector_type(4)));

// ---------------------------------------------------------------------------
// make_gates: build 36 fused 2x2 gates G = RY(p2)@RZ(p1)@RY(p0) (R4-verified),
// then 9 group matrices (layer l, group g of 4 wires) as real 32x32 f16:
//   W[s][n][k], s = l*3+g, n = reim'*16+t', k = reim*16+t,
//   U[t'][t] = prod_j G_{l, wire=11-(4g+j)}[t'_j][t_j]  (complex 16x16)
//   W blocks: [[Ur, -Ui],[Ui, Ur]]  (row n, col k)
// Stored exactly as the MFMA B-operand wants: B[k][n] = W[n][k], k-contiguous.
// R5: 45 us on one CU -> parallelized to 36 blocks (each redundantly computes
// the 36 tiny 2x2s, then its 256-element slice of W).
// ---------------------------------------------------------------------------
__global__ void make_gates(const float* __restrict__ params, _Float16* __restrict__ Wout) {
    __shared__ float Gs[36 * 8];
    const int tid = threadIdx.x;
    if (tid < 36) {
        float p0 = params[tid * 3 + 0];
        float p1 = params[tid * 3 + 1];
        float p2 = params[tid * 3 + 2];
        float c0 = cosf(0.5f * p0), s0 = sinf(0.5f * p0);
        float ch = cosf(0.5f * p1), sh = sinf(0.5f * p1);
        float c2 = cosf(0.5f * p2), s2 = sinf(0.5f * p2);
        float pr = ch, pi = -sh;   // p = exp(-i p1/2)
        float qr = ch, qi = sh;    // q = conj(p)
        float A = c2 * c0, Bc = s2 * s0, Cc = c2 * s0, D = s2 * c0;
        float* g = &Gs[tid * 8];
        g[0] = A * pr - Bc * qr;  g[1] = A * pi - Bc * qi;   // g00
        g[2] = -Cc * pr - D * qr; g[3] = -Cc * pi - D * qi;  // g01
        g[4] = D * pr + Cc * qr;  g[5] = D * pi + Cc * qi;   // g10
        g[6] = -Bc * pr + A * qr; g[7] = -Bc * pi + A * qi;  // g11
    }
    __syncthreads();
    {
        int e = blockIdx.x * 256 + tid;   // 36 blocks x 256 = 9216
        int s = e >> 10, idx = e & 1023;
        int n = idx >> 5, k = idx & 31;
        int rp = n >> 4, tp = n & 15, rr = k >> 4, tt = k & 31 & 15;
        int l = s / 3, g = s - 3 * l;
        float ur = 1.f, ui = 0.f;
#pragma unroll
        for (int jj = 0; jj < 4; ++jj) {
            int wire = 11 - (4 * g + jj);           // bit jj of t <-> wire 11-(4g+jj)
            const float* gp = &Gs[(l * 12 + wire) * 8];
            int rb = (tp >> jj) & 1, cb = (tt >> jj) & 1;
            float gr = gp[(rb * 2 + cb) * 2], gi = gp[(rb * 2 + cb) * 2 + 1];
            float nr = ur * gr - ui * gi;
            float ni = ur * gi + ui * gr;
            ur = nr; ui = ni;
        }
        float val = (rp == 0) ? ((rr == 0) ? ur : -ui)
                              : ((rr == 0) ? ui : ur);
        Wout[e] = (_Float16)val;
    }
}

// suffix-xor = CNOT-chain permutation (R4-verified convention)
__device__ __forceinline__ int sfx(int v) {
    v ^= v >> 1; v ^= v >> 2; v ^= v >> 4; v ^= v >> 8;
    return v;
}

// LDS swizzle on the state buffer (f16 element offsets), R6: 3-bit version.
// Flips 8-f16-chunk bits [5:3] with XOR of bits [8:6]^[11:9], injecting the
// lane id u (which lives at off bits >=7 in every D-store pattern) into bank
// bits [4:2]. Paper-verified: g0-store 16->2-way, g1-store 16->2-way,
// PERMST ->2-way, A-read stays at its 1KB/access throughput floor (uniform
// 8 lanes/bank-quad). 2-way is free (m136). Bits [2:0] untouched -> 8-f16
// chunks stay contiguous (b128/b64-safe).
__device__ __forceinline__ int swzf(int off) {
    return off ^ (((((off >> 6) ^ (off >> 9)) & 7)) << 3);
}

// Layouts (step g, state index i, 8-bit row m, 4-bit t = target bits, reim):
//   off_g = m*32 + reim*16 + t
//   g=0: t = i[3:0]  (wires 8..11),  m = i>>4           (i = m<<4 | t)
//   g=1: t = i[7:4]  (wires 4..7),   m = i[9:8] | i[3:0]<<2 | i[11:10]<<6
//   g=2: t = i[11:8] (wires 0..3),   m = i[7:0]
// Row-orderings chosen so a lane's 4 D-rows (consecutive m) land at
// consecutive offsets in the NEXT layout -> b64 stores.

__global__ void __launch_bounds__(NTHREADS)
qsim_kernel(const float* __restrict__ x,
            const _Float16* __restrict__ Wg,
            const float* __restrict__ head_w,
            const float* __restrict__ head_b,
            float* __restrict__ out) {
    __shared__ __align__(16) _Float16 Sst[8192];   // 16 KB state (256 x 32 f16)
    __shared__ __align__(16) _Float16 Wl[9216];    // 18 KB group matrices
    __shared__ float wlo[64], whi[64];
    __shared__ float csx[NQ], snx[NQ];
    __shared__ float wred[NTHREADS / 64];

    const int t = threadIdx.x, b = blockIdx.x;

    for (int i = t; i < 9216 / 2; i += NTHREADS)
        ((uint32_t*)Wl)[i] = ((const uint32_t*)Wg)[i];
    if (t < NQ) {
        float xv = 0.5f * x[b * NQ + t];
        csx[t] = cosf(xv);
        snx[t] = sinf(xv);
    }
    if (t >= 64 && t < 128) {        // wsum low LUT: bits 0..5 <-> wires 11..6
        int v = t - 64; float s = 0.f;
#pragma unroll
        for (int be = 0; be < 6; ++be)
            s += ((v >> be) & 1) ? -head_w[11 - be] : head_w[11 - be];
        wlo[v] = s;
    }
    if (t >= 128 && t < 192) {       // wsum high LUT: bits 6..11 <-> wires 5..0
        int v = t - 128; float s = 0.f;
#pragma unroll
        for (int be = 0; be < 6; ++be)
            s += ((v >> be) & 1) ? -head_w[5 - be] : head_w[5 - be];
        whi[v] = s;
    }
    __syncthreads();

    // ---- Init: product state (RX encoding), L_0 layout ----
    // amp(i) = (-i)^popc(i) * prod_w (bit_{11-w}(i) ? sin : cos)(x_w/2)
    {
        int m = t & 255, reim = t >> 8;
        float magm = 1.f;
#pragma unroll
        for (int j = 0; j < 8; ++j)       // m bit j = state bit 4+j = wire 7-j
            magm *= ((m >> j) & 1) ? snx[7 - j] : csx[7 - j];
        float A2[4], B2[4];
#pragma unroll
        for (int v = 0; v < 4; ++v) {     // t bits 0,1 = wires 11,10; bits 2,3 = wires 9,8
            A2[v] = ((v & 1) ? snx[11] : csx[11]) * ((v & 2) ? snx[10] : csx[10]);
            B2[v] = ((v & 1) ? snx[9] : csx[9]) * ((v & 2) ? snx[8] : csx[8]);
        }
        int pm = __popc(m);
        h8 w0, w1;
#pragma unroll
        for (int tau = 0; tau < 16; ++tau) {
            float mag = magm * A2[tau & 3] * B2[tau >> 2];
            int p = (pm + __popc(tau)) & 3;
            bool nz = ((p & 1) == reim);
            bool neg = ((((p >> 1) & 1) ^ reim) != 0);
            float v = nz ? (neg ? -mag : mag) : 0.f;
            if (tau < 8) w0[tau] = (_Float16)v; else w1[tau - 8] = (_Float16)v;
        }
        int off = m * 32 + reim * 16;
        *(h8*)&Sst[swzf(off)] = w0;
        *(h8*)&Sst[swzf(off + 8)] = w1;
    }
    __syncthreads();

    const int u = t & 15;          // MFMA row/col lane id
    const int q = (t >> 4) & 3;    // MFMA quad
    const int wv = t >> 6;         // wave id (0..7); tiles wv and wv+8
    const int abase0 = swzf((wv * 16 + u) * 32 + q * 8);
    const int abase1 = swzf(((wv + 8) * 16 + u) * 32 + q * 8);
    const int wb = u * 32 + q * 8;
    const f4 Z = {0.f, 0.f, 0.f, 0.f};
    float racc = 0.f;

#define ST4F(off_, v0_, v1_, v2_, v3_) {                                     \
    h4 w_; w_.x = (_Float16)(v0_); w_.y = (_Float16)(v1_);                   \
    w_.z = (_Float16)(v2_); w_.w = (_Float16)(v3_);                          \
    *(h4*)&Sst[swzf(off_)] = w_; }

#define ST4(off_, c_) ST4F(off_, (c_).x, (c_).y, (c_).z, (c_).w)

#define MM(sW_)                                                              \
    {                                                                        \
        h8 bf0 = *(const h8*)&Wl[(sW_) + wb];                                \
        h8 bf1 = *(const h8*)&Wl[(sW_) + 512 + wb];                          \
        h8 a0 = *(const h8*)&Sst[abase0];                                    \
        h8 a1 = *(const h8*)&Sst[abase1];                                    \
        c00 = __builtin_amdgcn_mfma_f32_16x16x32_f16(a0, bf0, Z, 0, 0, 0);   \
        c01 = __builtin_amdgcn_mfma_f32_16x16x32_f16(a0, bf1, Z, 0, 0, 0);   \
        c10 = __builtin_amdgcn_mfma_f32_16x16x32_f16(a1, bf0, Z, 0, 0, 0);   \
        c11 = __builtin_amdgcn_mfma_f32_16x16x32_f16(a1, bf1, Z, 0, 0, 0);   \
        __syncthreads();                                                     \
    }

// layer-end store: CNOT suffix-xor folded in; 4 slots stay an aligned group,
// values XOR-permuted by e = s2(j0&3), s2(x) = x ^ (x>>1)
#define PST1(off_, e_, v_) {                                                 \
    bool e1_ = ((e_) & 1), e2_ = (((e_) & 2) != 0);                          \
    float b0_ = e1_ ? (v_).y : (v_).x, b1_ = e1_ ? (v_).x : (v_).y;          \
    float b2_ = e1_ ? (v_).w : (v_).z, b3_ = e1_ ? (v_).z : (v_).w;          \
    ST4F(off_, e2_ ? b2_ : b0_, e2_ ? b3_ : b1_,                             \
               e2_ ? b1_ : b3_, e2_ ? b0_ : b2_); }

#define PERMST(tau_, vh0_, vh1_) {                                           \
    int i0_ = u * 256 + (tau_) * 16 + q * 4;                                 \
    int j0_ = sfx(i0_);                                                      \
    int cc_ = j0_ & 3, e_ = cc_ ^ (cc_ >> 1);                                \
    int jb_ = j0_ ^ cc_;                                                     \
    int ob_ = ((jb_ >> 4) << 5) | (jb_ & 12);                                \
    PST1(ob_, e_, vh0_); PST1(ob_ + 16, e_, vh1_); }

#define MEAS(tau_, vh0_, vh1_) {                                             \
    int i0_ = u * 256 + (tau_) * 16 + q * 4;                                 \
    int j0_ = sfx(i0_);                                                      \
    int jl_ = j0_ & 63;                                                      \
    float wh_ = whi[j0_ >> 6];                                               \
    float W0_ = wlo[jl_] + wh_, W1_ = wlo[jl_ ^ 1] + wh_;                    \
    float W2_ = wlo[jl_ ^ 3] + wh_, W3_ = wlo[jl_ ^ 2] + wh_;                \
    racc = fmaf((vh0_).x * (vh0_).x + (vh1_).x * (vh1_).x, W0_, racc);       \
    racc = fmaf((vh0_).y * (vh0_).y + (vh1_).y * (vh1_).y, W1_, racc);       \
    racc = fmaf((vh0_).z * (vh0_).z + (vh1_).z * (vh1_).z, W2_, racc);       \
    racc = fmaf((vh0_).w * (vh0_).w + (vh1_).w * (vh1_).w, W3_, racc); }

#pragma unroll
    for (int l = 0; l < NL; ++l) {
        f4 c00, c01, c10, c11;
        // ---- g=0: wires 8..11 ----
        MM((l * 3 + 0) * 1024)
        {   // D rows (bits 4,5 of i) -> L_1 t-low bits
            int wv3 = wv & 3, wvh = wv >> 2;
            int mf0 = (wv3 | (u << 2) | (wvh << 6)) * 32;
            int mf1 = (wv3 | (u << 2) | ((wvh + 2) << 6)) * 32;
            ST4(mf0 + q * 4, c00); ST4(mf0 + 16 + q * 4, c01);
            ST4(mf1 + q * 4, c10); ST4(mf1 + 16 + q * 4, c11);
            __syncthreads();
        }
        // ---- g=1: wires 4..7 ----
        MM((l * 3 + 1) * 1024)
        {   // D rows (bits 8,9 of i) -> L_2 t-low bits
            int p4 = (wv * 4 + q) & 15;
            int bm = (p4 | (u << 4)) * 32 + (wv >> 2) * 4;
            ST4(bm, c00); ST4(bm + 16, c01);
            ST4(bm + 8, c10); ST4(bm + 24, c11);
            __syncthreads();
        }
        // ---- g=2: wires 0..3 ----
        MM((l * 3 + 2) * 1024)
        if (l < NL - 1) {
            PERMST(wv, c00, c01)
            PERMST(wv + 8, c10, c11)
            __syncthreads();
        } else {
            // measurement: |amp|^2 * wsum(sfx(i)), halves = re/im parts
            MEAS(wv, c00, c01)
            MEAS(wv + 8, c10, c11)
        }
    }

#pragma unroll
    for (int o = 32; o >= 1; o >>= 1) racc += __shfl_xor(racc, o, 64);
    if ((t & 63) == 0) wred[wv] = racc;
    __syncthreads();
    if (t == 0) {
        float r = head_b[0];
#pragma unroll
        for (int i = 0; i < NTHREADS / 64; ++i) r += wred[i];
        out[b] = r;
    }
}

extern "C" void kernel_launch(void* const* d_in, const int* in_sizes, int n_in,
                              void* d_out, int out_size, void* d_ws, size_t ws_size,
                              hipStream_t stream) {
    const float* x = (const float*)d_in[0];
    const float* params = (const float*)d_in[1];
    const float* head_w = (const float*)d_in[2];
    const float* head_b = (const float*)d_in[3];
    float* out = (float*)d_out;
    _Float16* gates = (_Float16*)d_ws;   // 9216 f16 = 18 KB
    int B = in_sizes[0] / NQ;

    hipLaunchKernelGGL(make_gates, dim3(36), dim3(256), 0, stream, params, gates);
    hipLaunchKernelGGL(qsim_kernel, dim3(B), dim3(NTHREADS), 0, stream,
                       x, gates, head_w, head_b, out);
}